// Round 7
// baseline (1258.962 us; speedup 1.0000x reference)
//
#include <hip/hip_runtime.h>
#include <hip/hip_bf16.h>

typedef _Float16 f16;
typedef _Float16 f16x8 __attribute__((ext_vector_type(8)));
typedef _Float16 f16x4 __attribute__((ext_vector_type(4)));
typedef _Float16 f16x2 __attribute__((ext_vector_type(2)));
typedef float f32x4 __attribute__((ext_vector_type(4)));
typedef unsigned long long ull;

#define B_ 64
#define T_ 32
#define L_ 49
#define F_ 512
#define H_ 512
#define A_ 256
#define E_ 256
#define V_ 32000
#define G4 2048    // 4*H
#define NS 32      // slice blocks (16 hidden idx = 64 gate-cols each)
#define SLOT 16    // flag padding: 16 uints = 64B

#define ALOAD32(p)     __hip_atomic_load((const unsigned*)(p), __ATOMIC_RELAXED, __HIP_MEMORY_SCOPE_AGENT)
#define ASTORE32(p, v) __hip_atomic_store((unsigned*)(p), (v), __ATOMIC_RELAXED, __HIP_MEMORY_SCOPE_AGENT)
#define ASTOREF(p, v)  __hip_atomic_store((float*)(p), (v), __ATOMIC_RELAXED, __HIP_MEMORY_SCOPE_AGENT)

#if defined(__has_builtin)
#if __has_builtin(__builtin_amdgcn_fdot2)
#define HAS_FDOT2 1
#endif
#endif

// ---------------------------------------------------------------- converts
__global__ void k_cvt_f16(const float* __restrict__ x, f16* __restrict__ y, int n4) {
    int i = blockIdx.x * 256 + threadIdx.x;
    if (i < n4) {
        float4 v = ((const float4*)x)[i];
        f16x4 h = {(f16)v.x, (f16)v.y, (f16)v.z, (f16)v.w};
        ((f16x4*)y)[i] = h;
    }
}

// transpose+convert: x f32 [R][C] -> y f16 [C][R]
__global__ void k_tcvt(const float* __restrict__ x, f16* __restrict__ y, int R, int C) {
    __shared__ float ls[32][33];
    int c0 = blockIdx.x * 32, r0 = blockIdx.y * 32;
    int tid = threadIdx.x;
    int rr = tid >> 3, cs = (tid & 7) * 4;
    float4 v = *(const float4*)&x[(size_t)(r0 + rr) * C + c0 + cs];
    ls[rr][cs] = v.x; ls[rr][cs + 1] = v.y; ls[rr][cs + 2] = v.z; ls[rr][cs + 3] = v.w;
    __syncthreads();
    int cr = tid >> 3, rs = (tid & 7) * 4;
    f16x4 o = {(f16)ls[rs][cr], (f16)ls[rs + 1][cr], (f16)ls[rs + 2][cr], (f16)ls[rs + 3][cr]};
    *(f16x4*)&y[(size_t)(c0 + cr) * R + r0 + rs] = o;
}

// embedding gather -> fp16, row r = b*T + t
__global__ void k_emb(const float* __restrict__ emb, const int* __restrict__ cap,
                      f16* __restrict__ out) {
    int r = blockIdx.x;
    int tok = cap[r];
    out[(size_t)r * E_ + threadIdx.x] = (f16)emb[(size_t)tok * E_ + threadIdx.x];
}

// ---------------------------------------------------------------- init h0/c0 (h0 -> hslab[0] f16)
__global__ void k_init(const float* __restrict__ feats,
                       const float* __restrict__ Wh, const float* __restrict__ bh,
                       const float* __restrict__ Wc, const float* __restrict__ bc,
                       f16* __restrict__ hslab, float* __restrict__ c_cur) {
    __shared__ float mean[F_];
    int b = blockIdx.x, tid = threadIdx.x;
    for (int f = tid; f < F_; f += 256) {
        float s = 0.f;
        for (int l = 0; l < L_; ++l) s += feats[((size_t)b * L_ + l) * F_ + f];
        mean[f] = s * (1.f / 49.f);
    }
    __syncthreads();
    for (int h = tid; h < H_; h += 256) {
        float a = bh[h], c = bc[h];
        for (int k = 0; k < F_; ++k) {
            float m = mean[k];
            a += m * Wh[k * H_ + h];
            c += m * Wc[k * H_ + h];
        }
        hslab[(size_t)b * H_ + h] = (f16)a;
        c_cur[b * H_ + h] = c;
    }
}

// ---------------------------------------------------------------- feat_proj (fp32)
__global__ void k_featproj(const float* __restrict__ feats, const float* __restrict__ Wf,
                           const float* __restrict__ bf, float* __restrict__ out) {
    __shared__ float fs[16][F_];
    int r0 = blockIdx.x * 16, tid = threadIdx.x;
    for (int i = tid; i < 16 * F_; i += 256)
        fs[i >> 9][i & 511] = feats[(size_t)r0 * F_ + i];
    __syncthreads();
    float acc[16];
#pragma unroll
    for (int r = 0; r < 16; ++r) acc[r] = 0.f;
    for (int k = 0; k < F_; ++k) {
        float w = Wf[k * A_ + tid];
#pragma unroll
        for (int r = 0; r < 16; ++r) acc[r] += fs[r][k] * w;
    }
    float bb = bf[tid];
#pragma unroll
    for (int r = 0; r < 16; ++r) out[(size_t)(r0 + r) * A_ + tid] = acc[r] + bb;
}

// ---------------------------------------------------------------- 128x128 MFMA GEMM
// MODE 0: C f32 [rr*ldc+cc] + bias
// MODE 1: C f16 gate-permuted [(rr*512+(cc&511))*4+(cc>>9)]  (== rr*2048 + g*64 + c)
// MODE 2: C f32, input rows rr = t*64+b, output row remap -> (b*T+t)
struct Smem128 { f16 As[128][40]; f16 Bs[128][40]; };

template <int MODE>
__global__ __launch_bounds__(256) void k_gemm128(
    const f16* __restrict__ A, int lda, const f16* __restrict__ Bt, int ldb,
    void* __restrict__ Cv, int ldc, int M, int K, int mtiles,
    const float* __restrict__ bias0, const float* __restrict__ bias1) {
    __shared__ Smem128 sm;
    int bid = blockIdx.x;
    int m0 = (bid % mtiles) * 128, n0 = (bid / mtiles) * 128;
    int tid = threadIdx.x, lane = tid & 63, wave = tid >> 6;
    int wr = (wave >> 1) * 64, wc = (wave & 1) * 64;
    int frow = lane & 15, fk = (lane >> 4) * 8;
    int ra = tid >> 2, ka = (tid & 3) * 8;
    f32x4 acc[4][4];
#pragma unroll
    for (int i = 0; i < 4; ++i)
#pragma unroll
        for (int j = 0; j < 4; ++j) { acc[i][j][0]=0.f; acc[i][j][1]=0.f; acc[i][j][2]=0.f; acc[i][j][3]=0.f; }

    for (int k0 = 0; k0 < K; k0 += 32) {
        f16x8 a0 = *(const f16x8*)&A[(size_t)(m0 + ra) * lda + k0 + ka];
        f16x8 a1 = *(const f16x8*)&A[(size_t)(m0 + 64 + ra) * lda + k0 + ka];
        f16x8 b0 = *(const f16x8*)&Bt[(size_t)(n0 + ra) * ldb + k0 + ka];
        f16x8 b1 = *(const f16x8*)&Bt[(size_t)(n0 + 64 + ra) * ldb + k0 + ka];
        __syncthreads();
        *(f16x8*)&sm.As[ra][ka] = a0;
        *(f16x8*)&sm.As[64 + ra][ka] = a1;
        *(f16x8*)&sm.Bs[ra][ka] = b0;
        *(f16x8*)&sm.Bs[64 + ra][ka] = b1;
        __syncthreads();
        f16x8 av[4], bv[4];
#pragma unroll
        for (int i = 0; i < 4; ++i) {
            av[i] = *(f16x8*)&sm.As[wr + i * 16 + frow][fk];
            bv[i] = *(f16x8*)&sm.Bs[wc + i * 16 + frow][fk];
        }
#pragma unroll
        for (int mi = 0; mi < 4; ++mi)
#pragma unroll
            for (int ni = 0; ni < 4; ++ni)
                acc[mi][ni] = __builtin_amdgcn_mfma_f32_16x16x32_f16(av[mi], bv[ni], acc[mi][ni], 0, 0, 0);
    }
    int rq = (lane >> 4) * 4;
#pragma unroll
    for (int mi = 0; mi < 4; ++mi)
#pragma unroll
        for (int ni = 0; ni < 4; ++ni) {
            int cc = n0 + wc + ni * 16 + frow;
            float badd = (bias0 ? bias0[cc] : 0.f) + (bias1 ? bias1[cc] : 0.f);
#pragma unroll
            for (int r = 0; r < 4; ++r) {
                int rr = m0 + wr + mi * 16 + rq + r;
                if (rr < M) {
                    if (MODE == 0)
                        ((float*)Cv)[(size_t)rr * ldc + cc] = acc[mi][ni][r] + badd;
                    else if (MODE == 1)
                        ((f16*)Cv)[((size_t)rr * 512 + (cc & 511)) * 4 + (cc >> 9)] =
                            (f16)(acc[mi][ni][r] + badd);
                    else
                        ((float*)Cv)[((size_t)(rr & 63) * T_ + (rr >> 6)) * ldc + cc] =
                            acc[mi][ni][r] + badd;
                }
            }
        }
}

// ---------------------------------------------------------------- persistent recurrence
// 64 gate blocks: attention only (ea, scores, softmax) -> publish alpha (49 f32).
// 32 slice blocks: own 16 hidden idx each -> all 4 gate-cols -> hw in-block,
// LSTM pointwise in-block, c-state in registers, publish h(t+1) slice.
// One bulk handoff per step (h, 64KB); alpha broadcast overlaps MFMA.
struct SliceSm {
    f16 w[64][512];          // 64 KB, B-operand (rows = permuted cols c)
    union USm {
        f16 hs[64][512];     // 64 KB, A-operand stage
        struct { float hw[64][68]; float aL[64 * 52]; } gp;   // post-MFMA reuse
    } u;
};                           // 128 KB
struct GateSm {
    float fp[L_][A_];        // 50 KB
    float ea[A_];
    float ws[A_];
    float sc[64];
    unsigned hL[256];        // h(t)[b] as packed f16 pairs
};

__device__ __forceinline__ void wait_n(const unsigned* flags, int n, unsigned target) {
    int l = threadIdx.x & 63;
    if (l < n) {
        const unsigned* p = flags + l * SLOT;
        while (ALOAD32(p) < target) __builtin_amdgcn_s_sleep(1);
    }
    asm volatile("" ::: "memory");   // keep data loads after the poll
}

__device__ __forceinline__ float sigm(float x) { return 1.f / (1.f + __expf(-x)); }
__device__ __forceinline__ float tanh_f(float x) { return 1.f - 2.f / (1.f + __expf(2.f * x)); }

__global__ __launch_bounds__(256, 1) void k_steps(
    const f16* __restrict__ WhhT, const float* __restrict__ featproj,
    const f16* __restrict__ WhidT, const float* __restrict__ b_hid,
    const float* __restrict__ W_score, const float* __restrict__ b_score,
    const f16* __restrict__ embP, const f16* __restrict__ fp2P,
    const float* __restrict__ c_cur,
    f16* __restrict__ hslab, float* __restrict__ aslab,
    float* __restrict__ out_alpha,
    unsigned* __restrict__ sliceflag, unsigned* __restrict__ aflag) {
    __shared__ __align__(16) char smraw[sizeof(SliceSm)];
    int bid = blockIdx.x, tid = threadIdx.x;

    if (bid < 64) {
        // ============ gate/attention block for batch b ============
        int b = bid;
        GateSm* S = (GateSm*)smraw;
        for (int i = tid; i < L_ * A_; i += 256)
            ((float*)S->fp)[i] = featproj[(size_t)b * L_ * A_ + i];
        S->ws[tid] = W_score[tid];
        float bhid_r = b_hid[tid];
        float bsc = b_score[0];
        int wv = tid >> 6, ln = tid & 63;
        const unsigned* hsl32 = (const unsigned*)hslab;
        const f16* wrow = WhidT + (size_t)tid * 512;
        __syncthreads();

        for (int t = 0; t < T_; ++t) {
            wait_n(sliceflag, NS, (unsigned)t);      // h(t) ready (t=0 trivial)
            S->hL[tid] = hsl32[((size_t)t * B_ + b) * 256 + tid];
            __syncthreads();
            // ---- ea = h @ W_hid + b_hid (dot2 f16 MACs, f32 accum) ----
            {
                float acc = bhid_r;
                const f16x8* hL8 = (const f16x8*)S->hL;
#pragma unroll 8
                for (int kk = 0; kk < 64; ++kk) {
                    union { f16x8 v; f16x2 p[4]; } uw, uh;
                    uw.v = *(const f16x8*)&wrow[kk * 8];
                    uh.v = hL8[kk];
#ifdef HAS_FDOT2
                    acc = __builtin_amdgcn_fdot2(uw.p[0], uh.p[0], acc, false);
                    acc = __builtin_amdgcn_fdot2(uw.p[1], uh.p[1], acc, false);
                    acc = __builtin_amdgcn_fdot2(uw.p[2], uh.p[2], acc, false);
                    acc = __builtin_amdgcn_fdot2(uw.p[3], uh.p[3], acc, false);
#else
#pragma unroll
                    for (int e = 0; e < 8; ++e) acc += (float)uw.v[e] * (float)uh.v[e];
#endif
                }
                S->ea[tid] = acc;
            }
            __syncthreads();
            // ---- scores ----
            for (int l = wv; l < L_; l += 4) {
                float p = 0.f;
#pragma unroll
                for (int q = 0; q < 4; ++q) {
                    int j = ln + q * 64;
                    p += tanh_f(S->fp[l][j] + S->ea[j]) * S->ws[j];
                }
#pragma unroll
                for (int off = 32; off > 0; off >>= 1) p += __shfl_xor(p, off);
                if (ln == 0) S->sc[l] = p;
            }
            __syncthreads();
            // ---- softmax (wave 0) -> publish alpha ----
            if (tid < 64) {
                float v = (tid < L_) ? S->sc[tid] + bsc : -3.4e38f;
                float m = v;
#pragma unroll
                for (int off = 32; off > 0; off >>= 1) m = fmaxf(m, __shfl_xor(m, off));
                float e = (tid < L_) ? __expf(v - m) : 0.f;
                float s = e;
#pragma unroll
                for (int off = 32; off > 0; off >>= 1) s += __shfl_xor(s, off);
                if (tid < L_) {
                    float al = e / s;
                    ASTOREF(&aslab[((size_t)t * B_ + b) * 52 + tid], al);
                    out_alpha[((size_t)b * T_ + t) * L_ + tid] = al;
                }
            }
            __syncthreads();   // drains vmcnt: alpha sc1 stores acked
            if (tid == 0) ASTORE32(&aflag[b * SLOT], (unsigned)(t + 1));
        }
    } else {
        // ============ slice block g: hidden idx [16g,16g+16) ============
        int g = bid - 64;
        SliceSm* S = (SliceSm*)smraw;
        // stage W slice: LDS row c <- WhhT row (c&3)*512 + g*16 + (c>>2)
        for (int i = 0; i < 16; ++i) {
            int idx = i * 256 + tid;
            int r = idx >> 6, ch = idx & 63;
            int cc = (r & 3) * 512 + g * 16 + (r >> 2);
            *(f16x8*)&S->w[r][(ch ^ (r & 7)) * 8] =
                *(const f16x8*)&WhhT[(size_t)cc * 512 + ch * 8];
        }
        int wvv = tid >> 6, lane = tid & 63;
        int frow = lane & 15, q = lane >> 4, sw = frow & 7, rq = q * 4;
        int p = tid & 7, bb = tid >> 3;
        int b0 = bb, b1 = bb + 32;
        int j0 = g * 16 + 2 * p;
        float cs00 = c_cur[b0 * H_ + j0], cs01 = c_cur[b0 * H_ + j0 + 1];
        float cs10 = c_cur[b1 * H_ + j0], cs11 = c_cur[b1 * H_ + j0 + 1];
        float* hwL = &S->u.gp.hw[0][0];
        float* aL = S->u.gp.aL;
        unsigned* hsl32 = (unsigned*)hslab;
        __syncthreads();

        for (int t = 0; t < T_; ++t) {
            wait_n(sliceflag, NS, (unsigned)t);      // full h(t) ready
            // ---- gather h(t) 64x512 f16 (plain cached loads, fresh slab) ----
            {
                const f16* hsrc = hslab + (size_t)t * B_ * H_;
#pragma unroll
                for (int i = 0; i < 16; ++i) {
                    int idx = i * 256 + tid;
                    int r = idx >> 6, ch = idx & 63;
                    *(f16x8*)&S->u.hs[r][(ch ^ (r & 7)) * 8] =
                        *(const f16x8*)&hsrc[(size_t)r * H_ + ch * 8];
                }
            }
            __syncthreads();
            // ---- hw = h @ Wslice (64x64, K=512) ----
            f32x4 a4[4];
#pragma unroll
            for (int mi = 0; mi < 4; ++mi) { a4[mi][0]=0.f; a4[mi][1]=0.f; a4[mi][2]=0.f; a4[mi][3]=0.f; }
#pragma unroll
            for (int kk = 0; kk < 16; ++kk) {
                int ch = ((kk * 4 + q) ^ sw) * 8;
                f16x8 bv = *(f16x8*)&S->w[wvv * 16 + frow][ch];
#pragma unroll
                for (int mi = 0; mi < 4; ++mi) {
                    f16x8 av = *(f16x8*)&S->u.hs[mi * 16 + frow][ch];
                    a4[mi] = __builtin_amdgcn_mfma_f32_16x16x32_f16(av, bv, a4[mi], 0, 0, 0);
                }
            }
            // ---- wait alpha(t), then repurpose hs-LDS as hw + aL ----
            wait_n(aflag, 64, (unsigned)(t + 1));
            __syncthreads();   // all MFMA hs reads complete before overwrite
#pragma unroll
            for (int mi = 0; mi < 4; ++mi)
#pragma unroll
                for (int r = 0; r < 4; ++r)
                    hwL[(mi * 16 + rq + r) * 68 + wvv * 16 + frow] = a4[mi][r];
            for (int i = tid; i < 64 * 52; i += 256)
                aL[i] = aslab[(size_t)t * B_ * 52 + i];   // plain, fresh slab
            __syncthreads();
            // ---- gates: ep + hw + sum_l alpha*fp2, then LSTM pointwise ----
            {
                const f16* fpb0 = fp2P + (size_t)b0 * L_ * G4 + g * 64 + 8 * p;
                const f16* fpb1 = fp2P + (size_t)b1 * L_ * G4 + g * 64 + 8 * p;
                f16x8 ep0 = *(const f16x8*)&embP[((size_t)b0 * T_ + t) * G4 + g * 64 + 8 * p];
                f16x8 ep1 = *(const f16x8*)&embP[((size_t)b1 * T_ + t) * G4 + g * 64 + 8 * p];
                float gA[8], gB[8];
#pragma unroll
                for (int i = 0; i < 8; ++i) {
                    gA[i] = hwL[b0 * 68 + 8 * p + i] + (float)ep0[i];
                    gB[i] = hwL[b1 * 68 + 8 * p + i] + (float)ep1[i];
                }
#pragma unroll 7
                for (int l = 0; l < L_; ++l) {
                    float al0 = aL[b0 * 52 + l], al1 = aL[b1 * 52 + l];
                    f16x8 f0 = *(const f16x8*)&fpb0[(size_t)l * G4];
                    f16x8 f1 = *(const f16x8*)&fpb1[(size_t)l * G4];
#pragma unroll
                    for (int i = 0; i < 8; ++i) {
                        gA[i] += al0 * (float)f0[i];
                        gB[i] += al1 * (float)f1[i];
                    }
                }
                // pointwise (gate order i,f,g,o at c = 8p + {0..3}, {4..7})
                float cn00 = sigm(gA[1]) * cs00 + sigm(gA[0]) * tanh_f(gA[2]);
                float cn01 = sigm(gA[5]) * cs01 + sigm(gA[4]) * tanh_f(gA[6]);
                float cn10 = sigm(gB[1]) * cs10 + sigm(gB[0]) * tanh_f(gB[2]);
                float cn11 = sigm(gB[5]) * cs11 + sigm(gB[4]) * tanh_f(gB[6]);
                float h00 = sigm(gA[3]) * tanh_f(cn00);
                float h01 = sigm(gA[7]) * tanh_f(cn01);
                float h10 = sigm(gB[3]) * tanh_f(cn10);
                float h11 = sigm(gB[7]) * tanh_f(cn11);
                cs00 = cn00; cs01 = cn01; cs10 = cn10; cs11 = cn11;
                union { f16 h[2]; unsigned u; } pk0, pk1;
                pk0.h[0] = (f16)h00; pk0.h[1] = (f16)h01;
                pk1.h[0] = (f16)h10; pk1.h[1] = (f16)h11;
                ASTORE32(hsl32 + ((size_t)(t + 1) * B_ + b0) * 256 + g * 8 + p, pk0.u);
                ASTORE32(hsl32 + ((size_t)(t + 1) * B_ + b1) * 256 + g * 8 + p, pk1.u);
            }
            __syncthreads();   // drains vmcnt: h sc1 stores acked
            if (tid == 0) ASTORE32(&sliceflag[g * SLOT], (unsigned)(t + 1));
        }
    }
}

// ---------------------------------------------------------------- launch
extern "C" void kernel_launch(void* const* d_in, const int* in_sizes, int n_in,
                              void* d_out, int out_size, void* d_ws, size_t ws_size,
                              hipStream_t stream) {
    const float* image_feats = (const float*)d_in[0];
    const int*   caption     = (const int*)d_in[1];
    const float* embedding   = (const float*)d_in[2];
    const float* W_init_h    = (const float*)d_in[3];
    const float* b_init_h    = (const float*)d_in[4];
    const float* W_init_c    = (const float*)d_in[5];
    const float* b_init_c    = (const float*)d_in[6];
    const float* W_feat      = (const float*)d_in[7];
    const float* b_feat      = (const float*)d_in[8];
    const float* W_hid       = (const float*)d_in[9];
    const float* b_hid       = (const float*)d_in[10];
    const float* W_score     = (const float*)d_in[11];
    const float* b_score     = (const float*)d_in[12];
    const float* W_ih        = (const float*)d_in[13];
    const float* b_ih        = (const float*)d_in[14];
    const float* W_hh        = (const float*)d_in[15];
    const float* b_hh        = (const float*)d_in[16];
    const float* W_out       = (const float*)d_in[17];
    const float* b_out       = (const float*)d_in[18];

    float* preds = (float*)d_out;                                   // (B,T,V)
    float* out_alpha = preds + (size_t)B_ * T_ * V_;                // (B,T,L)

    size_t off = 0;
    char* base = (char*)d_ws;
    auto carve = [&](size_t bytes) {
        void* p = base + off;
        off += (bytes + 255) & ~(size_t)255;
        return p;
    };
    const int MP = 3200;  // B*L=3136 padded to 25*128
    f16* fp2P      = (f16*)carve((size_t)MP * G4 * 2);              // 13.1 MB
    f16* embP      = (f16*)carve((size_t)B_ * T_ * G4 * 2);         // 8.4 MB
    float* featproj = (float*)carve((size_t)B_ * L_ * A_ * 4);      // 3.2 MB
    float* c_cur   = (float*)carve((size_t)B_ * H_ * 4);
    f16* hslab     = (f16*)carve((size_t)(T_ + 1) * B_ * H_ * 2);   // 2.1 MB
    float* aslab   = (float*)carve((size_t)T_ * B_ * 52 * 4);       // 426 KB
    unsigned* flags = (unsigned*)carve(128 * SLOT * 4);
    f16* feats16   = (f16*)carve((size_t)MP * F_ * 2);
    f16* embs16    = (f16*)carve((size_t)B_ * T_ * E_ * 2);
    f16* WihT      = (f16*)carve((size_t)G4 * (E_ + F_) * 2);
    f16* WhhT      = (f16*)carve((size_t)G4 * H_ * 2);
    f16* WoutT     = (f16*)carve((size_t)V_ * H_ * 2);
    f16* WhidT     = (f16*)carve((size_t)A_ * H_ * 2);              // [256][512]
    unsigned* sliceflag = flags;
    unsigned* aflag     = flags + 64 * SLOT;
    (void)ws_size; (void)in_sizes; (void)n_in; (void)out_size;

    hipLaunchKernelGGL(k_tcvt, dim3(G4 / 32, (E_ + F_) / 32), dim3(256), 0, stream,
                       W_ih, WihT, E_ + F_, G4);
    hipLaunchKernelGGL(k_tcvt, dim3(G4 / 32, H_ / 32), dim3(256), 0, stream,
                       W_hh, WhhT, H_, G4);
    hipLaunchKernelGGL(k_tcvt, dim3(V_ / 32, H_ / 32), dim3(256), 0, stream,
                       W_out, WoutT, H_, V_);
    hipLaunchKernelGGL(k_tcvt, dim3(A_ / 32, H_ / 32), dim3(256), 0, stream,
                       W_hid, WhidT, H_, A_);
    {
        int n4 = (int)((size_t)B_ * L_ * F_ / 4);
        hipLaunchKernelGGL(k_cvt_f16, dim3((n4 + 255) / 256), dim3(256), 0, stream,
                           image_feats, feats16, n4);
    }
    hipLaunchKernelGGL(k_emb, dim3(B_ * T_), dim3(E_), 0, stream, embedding, caption, embs16);
    hipLaunchKernelGGL(k_init, dim3(B_), dim3(256), 0, stream,
                       image_feats, W_init_h, b_init_h, W_init_c, b_init_c,
                       hslab, c_cur);
    hipLaunchKernelGGL(k_featproj, dim3(B_ * L_ / 16), dim3(256), 0, stream,
                       image_feats, W_feat, b_feat, featproj);
    // fp2P (f16, gate-permuted) = feats @ W_ih[E:,:]
    hipLaunchKernelGGL(HIP_KERNEL_NAME(k_gemm128<1>), dim3(25 * (G4 / 128)), dim3(256), 0, stream,
                       feats16, F_, WihT + E_, E_ + F_,
                       (void*)fp2P, G4, MP, F_, 25,
                       (const float*)nullptr, (const float*)nullptr);
    // embP (f16, gate-permuted) = embs @ W_ih[:E,:] + b_ih + b_hh
    hipLaunchKernelGGL(HIP_KERNEL_NAME(k_gemm128<1>), dim3((B_ * T_ / 128) * (G4 / 128)), dim3(256), 0, stream,
                       embs16, E_, WihT, E_ + F_,
                       (void*)embP, G4, B_ * T_, E_, B_ * T_ / 128,
                       b_ih, b_hh);
    // persistent recurrence: 64 gate + 32 slice blocks
    hipMemsetAsync(flags, 0, 128 * SLOT * 4, stream);
    hipLaunchKernelGGL(k_steps, dim3(64 + NS), dim3(256), 0, stream,
                       WhhT, featproj, WhidT, b_hid, W_score, b_score,
                       embP, fp2P, c_cur, hslab, aslab, out_alpha,
                       sliceflag, aflag);
    // predictions = hslab[1..32] @ W_out + b_out  (rows t*64+b -> out row b*T+t)
    hipLaunchKernelGGL(HIP_KERNEL_NAME(k_gemm128<2>), dim3((B_ * T_ / 128) * (V_ / 128)), dim3(256), 0, stream,
                       hslab + (size_t)B_ * H_, H_, WoutT, H_,
                       (void*)preds, V_, B_ * T_, H_, B_ * T_ / 128,
                       b_out, (const float*)nullptr);
}

// Round 8
// 852.913 us; speedup vs baseline: 1.4761x; 1.4761x over previous
//
#include <hip/hip_runtime.h>
#include <hip/hip_bf16.h>

typedef _Float16 f16;
typedef _Float16 f16x8 __attribute__((ext_vector_type(8)));
typedef _Float16 f16x4 __attribute__((ext_vector_type(4)));
typedef _Float16 f16x2 __attribute__((ext_vector_type(2)));
typedef float f32x4 __attribute__((ext_vector_type(4)));
typedef unsigned long long ull;

#define B_ 64
#define T_ 32
#define L_ 49
#define F_ 512
#define H_ 512
#define A_ 256
#define E_ 256
#define V_ 32000
#define G4 2048
#define NG 32      // gemm blocks: hidden slice of 16 -> 64 permuted cols each
#define SLOT 16

#define ALOAD32(p)     __hip_atomic_load((const unsigned*)(p), __ATOMIC_RELAXED, __HIP_MEMORY_SCOPE_AGENT)
#define ASTORE32(p, v) __hip_atomic_store((unsigned*)(p), (v), __ATOMIC_RELAXED, __HIP_MEMORY_SCOPE_AGENT)
#define ASTORE64(p, v) __hip_atomic_store((ull*)(p), (v), __ATOMIC_RELAXED, __HIP_MEMORY_SCOPE_AGENT)
#define AADD(p)        __hip_atomic_fetch_add((unsigned*)(p), 1u, __ATOMIC_RELAXED, __HIP_MEMORY_SCOPE_AGENT)

#if defined(__has_builtin)
#if __has_builtin(__builtin_amdgcn_fdot2)
#define HAS_FDOT2 1
#endif
#endif

// ================================================================ fused prologue
// segments: 4x transpose-convert, feats cvt, emb gather, init h0/c0, featproj
#define NB_TC0 (64 * 24)     // W_ih  [768][2048] -> WihT  [2048][768]
#define NB_TC1 (64 * 16)     // W_hh  [512][2048] -> WhhT  [2048][512]
#define NB_TC2 (1000 * 16)   // W_out [512][32000]-> WoutT [32000][512]
#define NB_TC3 (8 * 16)      // W_hid [512][256]  -> WhidT [256][512]
#define NB_CVT 1568          // feats -> f16 (401408 float4)
#define NB_EMB 2048          // B*T rows
#define NB_INIT 64
#define NB_FP  196           // B*L/16

__device__ void dev_tcvt(const float* __restrict__ x, f16* __restrict__ y,
                         int R, int C, int bx, int by, char* smem) {
    float (*ls)[33] = (float(*)[33])smem;
    int c0 = bx * 32, r0 = by * 32;
    int tid = threadIdx.x;
    int rr = tid >> 3, cs = (tid & 7) * 4;
    float4 v = *(const float4*)&x[(size_t)(r0 + rr) * C + c0 + cs];
    ls[rr][cs] = v.x; ls[rr][cs + 1] = v.y; ls[rr][cs + 2] = v.z; ls[rr][cs + 3] = v.w;
    __syncthreads();
    int cr = tid >> 3, rs = (tid & 7) * 4;
    f16x4 o = {(f16)ls[rs][cr], (f16)ls[rs + 1][cr], (f16)ls[rs + 2][cr], (f16)ls[rs + 3][cr]};
    *(f16x4*)&y[(size_t)(c0 + cr) * R + r0 + rs] = o;
}

__global__ __launch_bounds__(256) void k_prep(
    const float* __restrict__ image_feats, const int* __restrict__ caption,
    const float* __restrict__ embedding,
    const float* __restrict__ W_init_h, const float* __restrict__ b_init_h,
    const float* __restrict__ W_init_c, const float* __restrict__ b_init_c,
    const float* __restrict__ W_feat, const float* __restrict__ b_feat,
    const float* __restrict__ W_hid, const float* __restrict__ W_ih,
    const float* __restrict__ W_hh, const float* __restrict__ W_out,
    f16* __restrict__ feats16, f16* __restrict__ embs16,
    f16* __restrict__ WihT, f16* __restrict__ WhhT,
    f16* __restrict__ WoutT, f16* __restrict__ WhidT,
    f16* __restrict__ hslab, float* __restrict__ c_cur,
    float* __restrict__ featproj) {
    __shared__ __align__(16) char smem[32768];
    int bid = blockIdx.x, tid = threadIdx.x;
    int r = bid;
    if (r < NB_TC0) { dev_tcvt(W_ih, WihT, E_ + F_, G4, r % 64, r / 64, smem); return; }
    r -= NB_TC0;
    if (r < NB_TC1) { dev_tcvt(W_hh, WhhT, H_, G4, r % 64, r / 64, smem); return; }
    r -= NB_TC1;
    if (r < NB_TC2) { dev_tcvt(W_out, WoutT, H_, V_, r % 1000, r / 1000, smem); return; }
    r -= NB_TC2;
    if (r < NB_TC3) { dev_tcvt(W_hid, WhidT, H_, A_, r % 8, r / 8, smem); return; }
    r -= NB_TC3;
    if (r < NB_CVT) {
        int i = r * 256 + tid;
        float4 v = ((const float4*)image_feats)[i];
        f16x4 h = {(f16)v.x, (f16)v.y, (f16)v.z, (f16)v.w};
        ((f16x4*)feats16)[i] = h;
        return;
    }
    r -= NB_CVT;
    if (r < NB_EMB) {
        int tok = caption[r];
        embs16[(size_t)r * E_ + tid] = (f16)embedding[(size_t)tok * E_ + tid];
        return;
    }
    r -= NB_EMB;
    if (r < NB_INIT) {
        float* mean = (float*)smem;
        int b = r;
        for (int f = tid; f < F_; f += 256) {
            float s = 0.f;
            for (int l = 0; l < L_; ++l) s += image_feats[((size_t)b * L_ + l) * F_ + f];
            mean[f] = s * (1.f / 49.f);
        }
        __syncthreads();
        for (int h = tid; h < H_; h += 256) {
            float a = b_init_h[h], c = b_init_c[h];
            for (int k = 0; k < F_; ++k) {
                float m = mean[k];
                a += m * W_init_h[k * H_ + h];
                c += m * W_init_c[k * H_ + h];
            }
            hslab[(size_t)b * H_ + h] = (f16)a;
            c_cur[b * H_ + h] = c;
        }
        return;
    }
    r -= NB_INIT;
    {
        float (*fs)[F_] = (float(*)[F_])smem;
        int r0 = r * 16;
        for (int i = tid; i < 16 * F_; i += 256)
            fs[i >> 9][i & 511] = image_feats[(size_t)r0 * F_ + i];
        __syncthreads();
        float acc[16];
#pragma unroll
        for (int q = 0; q < 16; ++q) acc[q] = 0.f;
        for (int k = 0; k < F_; ++k) {
            float w = W_feat[k * A_ + tid];
#pragma unroll
            for (int q = 0; q < 16; ++q) acc[q] += fs[q][k] * w;
        }
        float bb = b_feat[tid];
#pragma unroll
        for (int q = 0; q < 16; ++q) featproj[(size_t)(r0 + q) * A_ + tid] = acc[q] + bb;
    }
}

// ================================================================ 128x128 MFMA GEMM
// MODE 1: C f16 gate-permuted [(rr*512+(cc&511))*4+(cc>>9)]
// MODE 2: C f32 + bias, input rows rr = t*64+b, output row remap -> (b*T+t)
struct Smem128 { f16 As[128][40]; f16 Bs[128][40]; };

template <int MODE>
__device__ __forceinline__ void gemm128_body(
    const f16* __restrict__ A, int lda, const f16* __restrict__ Bt, int ldb,
    void* __restrict__ Cv, int ldc, int M, int K, int mtiles, int bid,
    const float* __restrict__ bias0, const float* __restrict__ bias1, Smem128* sm) {
    int m0 = (bid % mtiles) * 128, n0 = (bid / mtiles) * 128;
    int tid = threadIdx.x, lane = tid & 63, wave = tid >> 6;
    int wr = (wave >> 1) * 64, wc = (wave & 1) * 64;
    int frow = lane & 15, fk = (lane >> 4) * 8;
    int ra = tid >> 2, ka = (tid & 3) * 8;
    f32x4 acc[4][4];
#pragma unroll
    for (int i = 0; i < 4; ++i)
#pragma unroll
        for (int j = 0; j < 4; ++j) { acc[i][j][0]=0.f; acc[i][j][1]=0.f; acc[i][j][2]=0.f; acc[i][j][3]=0.f; }

    for (int k0 = 0; k0 < K; k0 += 32) {
        f16x8 a0 = *(const f16x8*)&A[(size_t)(m0 + ra) * lda + k0 + ka];
        f16x8 a1 = *(const f16x8*)&A[(size_t)(m0 + 64 + ra) * lda + k0 + ka];
        f16x8 b0 = *(const f16x8*)&Bt[(size_t)(n0 + ra) * ldb + k0 + ka];
        f16x8 b1 = *(const f16x8*)&Bt[(size_t)(n0 + 64 + ra) * ldb + k0 + ka];
        __syncthreads();
        *(f16x8*)&sm->As[ra][ka] = a0;
        *(f16x8*)&sm->As[64 + ra][ka] = a1;
        *(f16x8*)&sm->Bs[ra][ka] = b0;
        *(f16x8*)&sm->Bs[64 + ra][ka] = b1;
        __syncthreads();
        f16x8 av[4], bv[4];
#pragma unroll
        for (int i = 0; i < 4; ++i) {
            av[i] = *(f16x8*)&sm->As[wr + i * 16 + frow][fk];
            bv[i] = *(f16x8*)&sm->Bs[wc + i * 16 + frow][fk];
        }
#pragma unroll
        for (int mi = 0; mi < 4; ++mi)
#pragma unroll
            for (int ni = 0; ni < 4; ++ni)
                acc[mi][ni] = __builtin_amdgcn_mfma_f32_16x16x32_f16(av[mi], bv[ni], acc[mi][ni], 0, 0, 0);
    }
    int rq = (lane >> 4) * 4;
#pragma unroll
    for (int mi = 0; mi < 4; ++mi)
#pragma unroll
        for (int ni = 0; ni < 4; ++ni) {
            int cc = n0 + wc + ni * 16 + frow;
            float badd = (bias0 ? bias0[cc] : 0.f) + (bias1 ? bias1[cc] : 0.f);
#pragma unroll
            for (int r = 0; r < 4; ++r) {
                int rr = m0 + wr + mi * 16 + rq + r;
                if (rr < M) {
                    if (MODE == 1)
                        ((f16*)Cv)[((size_t)rr * 512 + (cc & 511)) * 4 + (cc >> 9)] =
                            (f16)(acc[mi][ni][r] + badd);
                    else
                        ((float*)Cv)[((size_t)(rr & 63) * T_ + (rr >> 6)) * ldc + cc] =
                            acc[mi][ni][r] + badd;
                }
            }
        }
}

// merged prologue GEMMs (both MODE 1): blocks < split do job0 (fp2P), rest job1 (embP)
__global__ __launch_bounds__(256) void k_gemm_pre(
    int split,
    const f16* A0, int lda0, const f16* B0, int ldb0, void* C0, int M0, int K0, int mt0,
    const f16* A1, int lda1, const f16* B1, int ldb1, void* C1, int M1, int K1, int mt1,
    const float* bias0, const float* bias1) {
    __shared__ Smem128 sm;
    int bid = blockIdx.x;
    if (bid < split)
        gemm128_body<1>(A0, lda0, B0, ldb0, C0, G4, M0, K0, mt0, bid,
                        (const float*)nullptr, (const float*)nullptr, &sm);
    else
        gemm128_body<1>(A1, lda1, B1, ldb1, C1, G4, M1, K1, mt1, bid - split,
                        bias0, bias1, &sm);
}

// logits GEMM with XCD-aware swizzle (grid 4000 = 8*500)
__global__ __launch_bounds__(256) void k_gemm_out(
    const f16* __restrict__ A, const f16* __restrict__ Bt,
    float* __restrict__ C, const float* __restrict__ bias) {
    __shared__ Smem128 sm;
    int bid = blockIdx.x;
    int swz = (bid & 7) * 500 + (bid >> 3);
    gemm128_body<2>(A, H_, Bt, H_, (void*)C, V_, B_ * T_, H_, B_ * T_ / 128, swz,
                    bias, (const float*)nullptr, &sm);
}

// ================================================================ persistent recurrence
// 64 gate blocks: attention + softmax + alpha*fp2 + pointwise (per batch, h/c local).
// 32 gemm blocks: hw = h @ Whh-slice (hidden j in [16g,16g+16), all 4 gates),
//                 LDS-resident weights, per-batch-contiguous hw output.
// Sync: per-step counters, single fetch_add per producer, lane-0 poll per consumer.
struct GateSm {
    float fp[L_][A_];       // 50 KB
    float ea[A_];
    float ws[A_];
    float sc[64];
    float alpha[64];
    unsigned hL[256];       // h(t) packed f16 pairs
};
struct GemmSm {
    f16 w[64][512];         // 64 KB (XOR-swizzled 16B chunks by row&7)
    union {
        f16 hs[64][512];    // 64 KB A-stage
        float hwT[64][68];  // post-MFMA transpose stage
    } u;
};

__device__ __forceinline__ void wait_cnt(const unsigned* p, unsigned target) {
    if (threadIdx.x == 0) {
        while (ALOAD32(p) < target) __builtin_amdgcn_s_sleep(1);
    }
    __syncthreads();
    asm volatile("" ::: "memory");
}

__device__ __forceinline__ float sigm(float x) { return 1.f / (1.f + __expf(-x)); }
__device__ __forceinline__ float tanh_f(float x) { return 1.f - 2.f / (1.f + __expf(2.f * x)); }

__global__ __launch_bounds__(256, 1) void k_steps(
    const f16* __restrict__ WhhT, const f16* __restrict__ WhidT,
    const float* __restrict__ featproj, const float* __restrict__ b_hid,
    const float* __restrict__ W_score, const float* __restrict__ b_score,
    const f16* __restrict__ embP, const f16* __restrict__ fp2P,
    const float* __restrict__ c_cur,
    f16* __restrict__ hslab, float* __restrict__ hwslab,
    float* __restrict__ out_alpha,
    unsigned* __restrict__ cntH, unsigned* __restrict__ cntW) {
    __shared__ __align__(16) char smraw[sizeof(GemmSm)];
    int bid = blockIdx.x, tid = threadIdx.x;

    if (bid < 64) {
        // ======== gate block for batch b ========
        int b = bid;
        GateSm* S = (GateSm*)smraw;
        for (int i = tid; i < L_ * A_; i += 256)
            ((float*)S->fp)[i] = featproj[(size_t)b * L_ * A_ + i];
        S->ws[tid] = W_score[tid];
        float bhid_r = b_hid[tid];
        float bsc = b_score[0];
        S->hL[tid] = ((const unsigned*)hslab)[(size_t)b * 256 + tid];  // h0 (k_prep)
        float cs0 = c_cur[b * H_ + 2 * tid], cs1 = c_cur[b * H_ + 2 * tid + 1];
        const f16* wrow = WhidT + (size_t)tid * 512;
        int wv = tid >> 6, ln = tid & 63;
        __syncthreads();

        for (int t = 0; t < T_; ++t) {
            // ---- ea = h @ W_hid + b_hid (f16 dot2, local h) ----
            {
                float acc = bhid_r;
                const f16x8* hL8 = (const f16x8*)S->hL;
#pragma unroll 16
                for (int kk = 0; kk < 64; ++kk) {
                    union { f16x8 v; f16x2 p[4]; } uw, uh;
                    uw.v = *(const f16x8*)&wrow[kk * 8];
                    uh.v = hL8[kk];
#ifdef HAS_FDOT2
                    acc = __builtin_amdgcn_fdot2(uw.p[0], uh.p[0], acc, false);
                    acc = __builtin_amdgcn_fdot2(uw.p[1], uh.p[1], acc, false);
                    acc = __builtin_amdgcn_fdot2(uw.p[2], uh.p[2], acc, false);
                    acc = __builtin_amdgcn_fdot2(uw.p[3], uh.p[3], acc, false);
#else
#pragma unroll
                    for (int e = 0; e < 8; ++e) acc += (float)uw.v[e] * (float)uh.v[e];
#endif
                }
                S->ea[tid] = acc;
            }
            __syncthreads();
            // ---- scores ----
            for (int l = wv; l < L_; l += 4) {
                float p = 0.f;
#pragma unroll
                for (int q = 0; q < 4; ++q) {
                    int j = ln + q * 64;
                    p += tanh_f(S->fp[l][j] + S->ea[j]) * S->ws[j];
                }
#pragma unroll
                for (int off = 32; off > 0; off >>= 1) p += __shfl_xor(p, off);
                if (ln == 0) S->sc[l] = p;
            }
            __syncthreads();
            // ---- softmax (wave 0) ----
            if (tid < 64) {
                float v = (tid < L_) ? S->sc[tid] + bsc : -3.4e38f;
                float m = v;
#pragma unroll
                for (int off = 32; off > 0; off >>= 1) m = fmaxf(m, __shfl_xor(m, off));
                float e = (tid < L_) ? __expf(v - m) : 0.f;
                float s = e;
#pragma unroll
                for (int off = 32; off > 0; off >>= 1) s += __shfl_xor(s, off);
                if (tid < L_) {
                    float al = e / s;
                    S->alpha[tid] = al;
                    out_alpha[((size_t)b * T_ + t) * L_ + tid] = al;
                }
            }
            __syncthreads();
            // ---- alpha-weighted fp2 partial sums (overlaps gemm blocks) ----
            float s8[8];
#pragma unroll
            for (int i = 0; i < 8; ++i) s8[i] = 0.f;
            {
                const f16* fpb = fp2P + (size_t)b * L_ * G4 + 8 * tid;
#pragma unroll 7
                for (int l = 0; l < L_; ++l) {
                    float a = S->alpha[l];
                    f16x8 fv = *(const f16x8*)&fpb[(size_t)l * G4];
#pragma unroll
                    for (int i = 0; i < 8; ++i) s8[i] += a * (float)fv[i];
                }
            }
            f16x8 ep = *(const f16x8*)&embP[((size_t)b * T_ + t) * G4 + 8 * tid];
            // ---- wait recurrent matmul, read hw (per-batch contiguous) ----
            wait_cnt(&cntW[t * SLOT], NG);
            {
                const float* hwp = hwslab + ((size_t)t * B_ + b) * G4 + 8 * tid;
                float4 h0 = *(const float4*)hwp;
                float4 h1 = *(const float4*)(hwp + 4);
                float gA[8];
                gA[0] = h0.x + (float)ep[0] + s8[0];
                gA[1] = h0.y + (float)ep[1] + s8[1];
                gA[2] = h0.z + (float)ep[2] + s8[2];
                gA[3] = h0.w + (float)ep[3] + s8[3];
                gA[4] = h1.x + (float)ep[4] + s8[4];
                gA[5] = h1.y + (float)ep[5] + s8[5];
                gA[6] = h1.z + (float)ep[6] + s8[6];
                gA[7] = h1.w + (float)ep[7] + s8[7];
                float cn0 = sigm(gA[1]) * cs0 + sigm(gA[0]) * tanh_f(gA[2]);
                float cn1 = sigm(gA[5]) * cs1 + sigm(gA[4]) * tanh_f(gA[6]);
                float hn0 = sigm(gA[3]) * tanh_f(cn0);
                float hn1 = sigm(gA[7]) * tanh_f(cn1);
                cs0 = cn0; cs1 = cn1;
                union { f16 h[2]; unsigned u; } pk;
                pk.h[0] = (f16)hn0; pk.h[1] = (f16)hn1;
                S->hL[tid] = pk.u;
                ASTORE32((unsigned*)hslab + ((size_t)(t + 1) * B_ + b) * 256 + tid, pk.u);
            }
            __syncthreads();   // drains vmcnt (h sc1 stores acked) + hL visible
            if (tid == 0) AADD(&cntH[(t + 1) * SLOT]);
        }
    } else {
        // ======== gemm block g: hidden j in [16g,16g+16) ========
        int g = bid - 64;
        GemmSm* S = (GemmSm*)smraw;
        // stage W slice: LDS row r (local pc) <- WhhT row (r&3)*512 + 16g + (r>>2)
        for (int i = 0; i < 16; ++i) {
            int idx = i * 256 + tid;
            int r = idx >> 6, ch = idx & 63;
            int cc = (r & 3) * 512 + 16 * g + (r >> 2);
            *(f16x8*)&S->w[r][(ch ^ (r & 7)) * 8] =
                *(const f16x8*)&WhhT[(size_t)cc * 512 + ch * 8];
        }
        int wvv = tid >> 6, lane = tid & 63;
        int frow = lane & 15, q = lane >> 4, sw = frow & 7, rq = q * 4;
        int bo = tid >> 2, cq = (tid & 3) * 16;   // store coords
        __syncthreads();

        for (int t = 0; t < T_; ++t) {
            if (t) wait_cnt(&cntH[t * SLOT], 64);
            // gather h(t): plain coalesced loads of fresh slab
            {
                const f16* hsrc = hslab + (size_t)t * B_ * H_;
#pragma unroll
                for (int i = 0; i < 16; ++i) {
                    int idx = i * 256 + tid;
                    int r = idx >> 6, ch = idx & 63;
                    *(f16x8*)&S->u.hs[r][(ch ^ (r & 7)) * 8] =
                        *(const f16x8*)&hsrc[(size_t)r * H_ + ch * 8];
                }
            }
            __syncthreads();
            f32x4 a4[4];
#pragma unroll
            for (int mi = 0; mi < 4; ++mi) { a4[mi][0]=0.f; a4[mi][1]=0.f; a4[mi][2]=0.f; a4[mi][3]=0.f; }
#pragma unroll
            for (int kk = 0; kk < 16; ++kk) {
                int ch = ((kk * 4 + q) ^ sw) * 8;
                f16x8 bv = *(f16x8*)&S->w[wvv * 16 + frow][ch];
#pragma unroll
                for (int mi = 0; mi < 4; ++mi) {
                    f16x8 av = *(f16x8*)&S->u.hs[mi * 16 + frow][ch];
                    a4[mi] = __builtin_amdgcn_mfma_f32_16x16x32_f16(av, bv, a4[mi], 0, 0, 0);
                }
            }
            __syncthreads();   // hs reads done before hwT overwrite
#pragma unroll
            for (int mi = 0; mi < 4; ++mi)
#pragma unroll
                for (int r = 0; r < 4; ++r)
                    S->u.hwT[mi * 16 + rq + r][wvv * 16 + frow] = a4[mi][r];
            __syncthreads();
            // coalesced sc1 stores: 64B per thread into hwslab[t][b][64g + c]
            {
                float* dst = hwslab + ((size_t)t * B_ + bo) * G4 + 64 * g + cq;
                const float* src = &S->u.hwT[bo][cq];
#pragma unroll
                for (int e = 0; e < 8; ++e) {
                    union { float f[2]; ull u; } pk;
                    pk.f[0] = src[2 * e]; pk.f[1] = src[2 * e + 1];
                    ASTORE64(dst + 2 * e, pk.u);
                }
            }
            __syncthreads();   // drains vmcnt: hw stores acked
            if (tid == 0) AADD(&cntW[t * SLOT]);
        }
    }
}

// ================================================================ launch
extern "C" void kernel_launch(void* const* d_in, const int* in_sizes, int n_in,
                              void* d_out, int out_size, void* d_ws, size_t ws_size,
                              hipStream_t stream) {
    const float* image_feats = (const float*)d_in[0];
    const int*   caption     = (const int*)d_in[1];
    const float* embedding   = (const float*)d_in[2];
    const float* W_init_h    = (const float*)d_in[3];
    const float* b_init_h    = (const float*)d_in[4];
    const float* W_init_c    = (const float*)d_in[5];
    const float* b_init_c    = (const float*)d_in[6];
    const float* W_feat      = (const float*)d_in[7];
    const float* b_feat      = (const float*)d_in[8];
    const float* W_hid       = (const float*)d_in[9];
    const float* b_hid       = (const float*)d_in[10];
    const float* W_score     = (const float*)d_in[11];
    const float* b_score     = (const float*)d_in[12];
    const float* W_ih        = (const float*)d_in[13];
    const float* b_ih        = (const float*)d_in[14];
    const float* W_hh        = (const float*)d_in[15];
    const float* b_hh        = (const float*)d_in[16];
    const float* W_out       = (const float*)d_in[17];
    const float* b_out       = (const float*)d_in[18];

    float* preds = (float*)d_out;                                   // (B,T,V)
    float* out_alpha = preds + (size_t)B_ * T_ * V_;                // (B,T,L)

    size_t off = 0;
    char* base = (char*)d_ws;
    auto carve = [&](size_t bytes) {
        void* p = base + off;
        off += (bytes + 255) & ~(size_t)255;
        return p;
    };
    const int MP = 3200;
    f16* fp2P       = (f16*)carve((size_t)MP * G4 * 2);             // 13.1 MB
    f16* embP       = (f16*)carve((size_t)B_ * T_ * G4 * 2);        // 8.4 MB
    float* featproj = (float*)carve((size_t)B_ * L_ * A_ * 4);      // 3.2 MB
    float* c_cur    = (float*)carve((size_t)B_ * H_ * 4);
    f16* hslab      = (f16*)carve((size_t)(T_ + 1) * B_ * H_ * 2);  // 2.1 MB
    float* hwslab   = (float*)carve((size_t)T_ * B_ * G4 * 4);      // 16 MB
    unsigned* cnts  = (unsigned*)carve(2 * (T_ + 2) * SLOT * 4);
    f16* feats16    = (f16*)carve((size_t)MP * F_ * 2);
    f16* embs16     = (f16*)carve((size_t)B_ * T_ * E_ * 2);
    f16* WihT       = (f16*)carve((size_t)G4 * (E_ + F_) * 2);
    f16* WhhT       = (f16*)carve((size_t)G4 * H_ * 2);
    f16* WoutT      = (f16*)carve((size_t)V_ * H_ * 2);
    f16* WhidT      = (f16*)carve((size_t)A_ * H_ * 2);
    unsigned* cntH = cnts;
    unsigned* cntW = cnts + (T_ + 2) * SLOT;
    (void)ws_size; (void)in_sizes; (void)n_in; (void)out_size;

    // 1) fused prologue
    {
        int nb = NB_TC0 + NB_TC1 + NB_TC2 + NB_TC3 + NB_CVT + NB_EMB + NB_INIT + NB_FP;
        hipLaunchKernelGGL(k_prep, dim3(nb), dim3(256), 0, stream,
                           image_feats, caption, embedding,
                           W_init_h, b_init_h, W_init_c, b_init_c,
                           W_feat, b_feat, W_hid, W_ih, W_hh, W_out,
                           feats16, embs16, WihT, WhhT, WoutT, WhidT,
                           hslab, c_cur, featproj);
    }
    // 2) merged prologue GEMMs: fp2P (400 blocks) + embP (256 blocks)
    hipLaunchKernelGGL(k_gemm_pre, dim3(400 + 256), dim3(256), 0, stream,
                       400,
                       feats16, F_, WihT + E_, E_ + F_, (void*)fp2P, B_ * L_, F_, 25,
                       embs16, E_, WihT, E_ + F_, (void*)embP, B_ * T_, E_, B_ * T_ / 128,
                       b_ih, b_hh);
    // 3) reset counters
    hipMemsetAsync(cnts, 0, 2 * (T_ + 2) * SLOT * 4, stream);
    // 4) persistent recurrence
    hipLaunchKernelGGL(k_steps, dim3(64 + NG), dim3(256), 0, stream,
                       WhhT, WhidT, featproj, b_hid, W_score, b_score,
                       embP, fp2P, c_cur, hslab, hwslab, out_alpha, cntH, cntW);
    // 5) logits = hslab[1..32] @ W_out + b_out (rows t*64+b -> out row b*T+t)
    hipLaunchKernelGGL(k_gemm_out, dim3(4000), dim3(256), 0, stream,
                       hslab + (size_t)B_ * H_, WoutT, preds, b_out);
}

// Round 9
// 772.352 us; speedup vs baseline: 1.6300x; 1.1043x over previous
//
#include <hip/hip_runtime.h>
#include <hip/hip_bf16.h>

typedef _Float16 f16;
typedef _Float16 f16x8 __attribute__((ext_vector_type(8)));
typedef _Float16 f16x4 __attribute__((ext_vector_type(4)));
typedef _Float16 f16x2 __attribute__((ext_vector_type(2)));
typedef float f32x4 __attribute__((ext_vector_type(4)));
typedef unsigned long long ull;

#define B_ 64
#define T_ 32
#define L_ 49
#define F_ 512
#define H_ 512
#define A_ 256
#define E_ 256
#define V_ 32000
#define G4 2048
#define NG 32       // recurrent-gemm blocks
#define NLOG 125    // logits blocks (256 cols each)
#define SLOT 16

#define ALOAD32(p)     __hip_atomic_load((const unsigned*)(p), __ATOMIC_RELAXED, __HIP_MEMORY_SCOPE_AGENT)
#define ASTORE32(p, v) __hip_atomic_store((unsigned*)(p), (v), __ATOMIC_RELAXED, __HIP_MEMORY_SCOPE_AGENT)
#define ASTORE64(p, v) __hip_atomic_store((ull*)(p), (v), __ATOMIC_RELAXED, __HIP_MEMORY_SCOPE_AGENT)
#define AADD(p)        __hip_atomic_fetch_add((unsigned*)(p), 1u, __ATOMIC_RELAXED, __HIP_MEMORY_SCOPE_AGENT)

#if defined(__has_builtin)
#if __has_builtin(__builtin_amdgcn_fdot2)
#define HAS_FDOT2 1
#endif
#endif

// ================================================================ fused prologue
#define NB_TC0 (64 * 24)     // W_ih  -> WihT  [2048][768]
#define NB_TC1 (64 * 16)     // W_hh  -> WhhT  [2048][512]
#define NB_TC2 (1000 * 16)   // W_out -> WoutT [32000][512]
#define NB_TC3 (8 * 16)      // W_hid -> WhidT [256][512]
#define NB_CVT 1568
#define NB_EMB 2048
#define NB_INIT 64
#define NB_FP  196

__device__ void dev_tcvt(const float* __restrict__ x, f16* __restrict__ y,
                         int R, int C, int bx, int by, char* smem) {
    float (*ls)[33] = (float(*)[33])smem;
    int c0 = bx * 32, r0 = by * 32;
    int tid = threadIdx.x;
    int rr = tid >> 3, cs = (tid & 7) * 4;
    float4 v = *(const float4*)&x[(size_t)(r0 + rr) * C + c0 + cs];
    ls[rr][cs] = v.x; ls[rr][cs + 1] = v.y; ls[rr][cs + 2] = v.z; ls[rr][cs + 3] = v.w;
    __syncthreads();
    int cr = tid >> 3, rs = (tid & 7) * 4;
    f16x4 o = {(f16)ls[rs][cr], (f16)ls[rs + 1][cr], (f16)ls[rs + 2][cr], (f16)ls[rs + 3][cr]};
    *(f16x4*)&y[(size_t)(c0 + cr) * R + r0 + rs] = o;
}

__global__ __launch_bounds__(256) void k_prep(
    const float* __restrict__ image_feats, const int* __restrict__ caption,
    const float* __restrict__ embedding,
    const float* __restrict__ W_init_h, const float* __restrict__ b_init_h,
    const float* __restrict__ W_init_c, const float* __restrict__ b_init_c,
    const float* __restrict__ W_feat, const float* __restrict__ b_feat,
    const float* __restrict__ W_hid, const float* __restrict__ W_ih,
    const float* __restrict__ W_hh, const float* __restrict__ W_out,
    f16* __restrict__ feats16, f16* __restrict__ embs16,
    f16* __restrict__ WihT, f16* __restrict__ WhhT,
    f16* __restrict__ WoutT, f16* __restrict__ WhidT,
    f16* __restrict__ hslab, float* __restrict__ c_cur,
    float* __restrict__ featproj) {
    __shared__ __align__(16) char smem[32768];
    int bid = blockIdx.x, tid = threadIdx.x;
    int r = bid;
    if (r < NB_TC0) { dev_tcvt(W_ih, WihT, E_ + F_, G4, r % 64, r / 64, smem); return; }
    r -= NB_TC0;
    if (r < NB_TC1) { dev_tcvt(W_hh, WhhT, H_, G4, r % 64, r / 64, smem); return; }
    r -= NB_TC1;
    if (r < NB_TC2) { dev_tcvt(W_out, WoutT, H_, V_, r % 1000, r / 1000, smem); return; }
    r -= NB_TC2;
    if (r < NB_TC3) { dev_tcvt(W_hid, WhidT, H_, A_, r % 8, r / 8, smem); return; }
    r -= NB_TC3;
    if (r < NB_CVT) {
        int i = r * 256 + tid;
        float4 v = ((const float4*)image_feats)[i];
        f16x4 h = {(f16)v.x, (f16)v.y, (f16)v.z, (f16)v.w};
        ((f16x4*)feats16)[i] = h;
        return;
    }
    r -= NB_CVT;
    if (r < NB_EMB) {
        int tok = caption[r];
        embs16[(size_t)r * E_ + tid] = (f16)embedding[(size_t)tok * E_ + tid];
        return;
    }
    r -= NB_EMB;
    if (r < NB_INIT) {
        float* mean = (float*)smem;
        int b = r;
        for (int f = tid; f < F_; f += 256) {
            float s = 0.f;
            for (int l = 0; l < L_; ++l) s += image_feats[((size_t)b * L_ + l) * F_ + f];
            mean[f] = s * (1.f / 49.f);
        }
        __syncthreads();
        for (int h = tid; h < H_; h += 256) {
            float a = b_init_h[h], c = b_init_c[h];
            for (int k = 0; k < F_; ++k) {
                float m = mean[k];
                a += m * W_init_h[k * H_ + h];
                c += m * W_init_c[k * H_ + h];
            }
            hslab[(size_t)b * H_ + h] = (f16)a;
            c_cur[b * H_ + h] = c;
        }
        return;
    }
    r -= NB_INIT;
    {
        float (*fs)[F_] = (float(*)[F_])smem;
        int r0 = r * 16;
        for (int i = tid; i < 16 * F_; i += 256)
            fs[i >> 9][i & 511] = image_feats[(size_t)r0 * F_ + i];
        __syncthreads();
        float acc[16];
#pragma unroll
        for (int q = 0; q < 16; ++q) acc[q] = 0.f;
        for (int k = 0; k < F_; ++k) {
            float w = W_feat[k * A_ + tid];
#pragma unroll
            for (int q = 0; q < 16; ++q) acc[q] += fs[q][k] * w;
        }
        float bb = b_feat[tid];
#pragma unroll
        for (int q = 0; q < 16; ++q) featproj[(size_t)(r0 + q) * A_ + tid] = acc[q] + bb;
    }
}

// ================================================================ 128x128 MFMA GEMM (prologue, MODE 1 only)
struct Smem128 { f16 As[128][40]; f16 Bs[128][40]; };

__device__ __forceinline__ void gemm128_body1(
    const f16* __restrict__ A, int lda, const f16* __restrict__ Bt, int ldb,
    f16* __restrict__ Cv, int M, int K, int mtiles, int bid,
    const float* __restrict__ bias0, const float* __restrict__ bias1, Smem128* sm) {
    int m0 = (bid % mtiles) * 128, n0 = (bid / mtiles) * 128;
    int tid = threadIdx.x, lane = tid & 63, wave = tid >> 6;
    int wr = (wave >> 1) * 64, wc = (wave & 1) * 64;
    int frow = lane & 15, fk = (lane >> 4) * 8;
    int ra = tid >> 2, ka = (tid & 3) * 8;
    f32x4 acc[4][4];
#pragma unroll
    for (int i = 0; i < 4; ++i)
#pragma unroll
        for (int j = 0; j < 4; ++j) { acc[i][j][0]=0.f; acc[i][j][1]=0.f; acc[i][j][2]=0.f; acc[i][j][3]=0.f; }

    for (int k0 = 0; k0 < K; k0 += 32) {
        f16x8 a0 = *(const f16x8*)&A[(size_t)(m0 + ra) * lda + k0 + ka];
        f16x8 a1 = *(const f16x8*)&A[(size_t)(m0 + 64 + ra) * lda + k0 + ka];
        f16x8 b0 = *(const f16x8*)&Bt[(size_t)(n0 + ra) * ldb + k0 + ka];
        f16x8 b1 = *(const f16x8*)&Bt[(size_t)(n0 + 64 + ra) * ldb + k0 + ka];
        __syncthreads();
        *(f16x8*)&sm->As[ra][ka] = a0;
        *(f16x8*)&sm->As[64 + ra][ka] = a1;
        *(f16x8*)&sm->Bs[ra][ka] = b0;
        *(f16x8*)&sm->Bs[64 + ra][ka] = b1;
        __syncthreads();
        f16x8 av[4], bv[4];
#pragma unroll
        for (int i = 0; i < 4; ++i) {
            av[i] = *(f16x8*)&sm->As[wr + i * 16 + frow][fk];
            bv[i] = *(f16x8*)&sm->Bs[wc + i * 16 + frow][fk];
        }
#pragma unroll
        for (int mi = 0; mi < 4; ++mi)
#pragma unroll
            for (int ni = 0; ni < 4; ++ni)
                acc[mi][ni] = __builtin_amdgcn_mfma_f32_16x16x32_f16(av[mi], bv[ni], acc[mi][ni], 0, 0, 0);
    }
    int rq = (lane >> 4) * 4;
#pragma unroll
    for (int mi = 0; mi < 4; ++mi)
#pragma unroll
        for (int ni = 0; ni < 4; ++ni) {
            int cc = n0 + wc + ni * 16 + frow;
            float badd = (bias0 ? bias0[cc] : 0.f) + (bias1 ? bias1[cc] : 0.f);
#pragma unroll
            for (int r = 0; r < 4; ++r) {
                int rr = m0 + wr + mi * 16 + rq + r;
                if (rr < M)
                    Cv[((size_t)rr * 512 + (cc & 511)) * 4 + (cc >> 9)] =
                        (f16)(acc[mi][ni][r] + badd);
            }
        }
}

__global__ __launch_bounds__(256) void k_gemm_pre(
    int split,
    const f16* A0, int lda0, const f16* B0, int ldb0, f16* C0, int M0, int K0, int mt0,
    const f16* A1, int lda1, const f16* B1, int ldb1, f16* C1, int M1, int K1, int mt1,
    const float* bias0, const float* bias1) {
    __shared__ Smem128 sm;
    int bid = blockIdx.x;
    if (bid < split)
        gemm128_body1(A0, lda0, B0, ldb0, C0, M0, K0, mt0, bid,
                      (const float*)nullptr, (const float*)nullptr, &sm);
    else
        gemm128_body1(A1, lda1, B1, ldb1, C1, M1, K1, mt1, bid - split,
                      bias0, bias1, &sm);
}

// ================================================================ persistent kernel
// 64 gate blocks  : attention + softmax + alpha*fp2 + LSTM pointwise (per batch)
// 32 gemm blocks  : hw = h @ Whh (hidden slice of 16, LDS weights), f16 handoff
// 125 logit blocks: 256-col W_out tile; per step t compute logits rows (.,t)
//                   from h(t+1) — runs in the recurrence's latency shadow.
struct GateSm {
    float fp[L_][A_];
    float ea[A_];
    float ws[A_];
    float sc[64];
    float alpha[64];
    unsigned hL[256];
};
struct GemmSm {
    f16 w[64][512];          // XOR-swizzled 16B chunks by row&7
    union {
        f16 hs[64][512];     // A-stage (swizzled)
        f16 hwT16[64][72];   // post-MFMA transpose stage (f16)
    } u;
};
struct LogSm { f16 hs[64][512]; };   // swizzled A-stage

__device__ __forceinline__ void wait_cnt(const unsigned* p, unsigned target) {
    if (threadIdx.x == 0) {
        while (ALOAD32(p) < target) __builtin_amdgcn_s_sleep(1);
    }
    __syncthreads();
    asm volatile("" ::: "memory");
}

__device__ __forceinline__ float sigm(float x) { return 1.f / (1.f + __expf(-x)); }
__device__ __forceinline__ float tanh_f(float x) { return 1.f - 2.f / (1.f + __expf(2.f * x)); }

__global__ __launch_bounds__(256, 1) void k_steps(
    const f16* __restrict__ WhhT, const f16* __restrict__ WhidT,
    const float* __restrict__ featproj, const float* __restrict__ b_hid,
    const float* __restrict__ W_score, const float* __restrict__ b_score,
    const f16* __restrict__ embP, const f16* __restrict__ fp2P,
    const float* __restrict__ c_cur,
    f16* __restrict__ hslab, f16* __restrict__ hwslab,
    const f16* __restrict__ WoutT, const float* __restrict__ b_out,
    float* __restrict__ preds, float* __restrict__ out_alpha,
    unsigned* __restrict__ cntH, unsigned* __restrict__ cntW,
    unsigned* __restrict__ cntH2) {
    __shared__ __align__(16) char smraw[sizeof(GemmSm)];
    int bid = blockIdx.x, tid = threadIdx.x;

    if (bid < 64) {
        // ======== gate block for batch b ========
        int b = bid;
        GateSm* S = (GateSm*)smraw;
        for (int i = tid; i < L_ * A_; i += 256)
            ((float*)S->fp)[i] = featproj[(size_t)b * L_ * A_ + i];
        S->ws[tid] = W_score[tid];
        float bhid_r = b_hid[tid];
        float bsc = b_score[0];
        S->hL[tid] = ((const unsigned*)hslab)[(size_t)b * 256 + tid];
        float cs0 = c_cur[b * H_ + 2 * tid], cs1 = c_cur[b * H_ + 2 * tid + 1];
        const f16* wrow = WhidT + (size_t)tid * 512;
        int wv = tid >> 6, ln = tid & 63;
        __syncthreads();

        for (int t = 0; t < T_; ++t) {
            // ---- ea = h @ W_hid + b_hid ----
            {
                float acc = bhid_r;
                const f16x8* hL8 = (const f16x8*)S->hL;
#pragma unroll 16
                for (int kk = 0; kk < 64; ++kk) {
                    union { f16x8 v; f16x2 p[4]; } uw, uh;
                    uw.v = *(const f16x8*)&wrow[kk * 8];
                    uh.v = hL8[kk];
#ifdef HAS_FDOT2
                    acc = __builtin_amdgcn_fdot2(uw.p[0], uh.p[0], acc, false);
                    acc = __builtin_amdgcn_fdot2(uw.p[1], uh.p[1], acc, false);
                    acc = __builtin_amdgcn_fdot2(uw.p[2], uh.p[2], acc, false);
                    acc = __builtin_amdgcn_fdot2(uw.p[3], uh.p[3], acc, false);
#else
#pragma unroll
                    for (int e = 0; e < 8; ++e) acc += (float)uw.v[e] * (float)uh.v[e];
#endif
                }
                S->ea[tid] = acc;
            }
            __syncthreads();
            // ---- scores ----
            for (int l = wv; l < L_; l += 4) {
                float p = 0.f;
#pragma unroll
                for (int q = 0; q < 4; ++q) {
                    int j = ln + q * 64;
                    p += tanh_f(S->fp[l][j] + S->ea[j]) * S->ws[j];
                }
#pragma unroll
                for (int off = 32; off > 0; off >>= 1) p += __shfl_xor(p, off);
                if (ln == 0) S->sc[l] = p;
            }
            __syncthreads();
            // ---- softmax (wave 0) ----
            if (tid < 64) {
                float v = (tid < L_) ? S->sc[tid] + bsc : -3.4e38f;
                float m = v;
#pragma unroll
                for (int off = 32; off > 0; off >>= 1) m = fmaxf(m, __shfl_xor(m, off));
                float e = (tid < L_) ? __expf(v - m) : 0.f;
                float s = e;
#pragma unroll
                for (int off = 32; off > 0; off >>= 1) s += __shfl_xor(s, off);
                if (tid < L_) {
                    float al = e / s;
                    S->alpha[tid] = al;
                    out_alpha[((size_t)b * T_ + t) * L_ + tid] = al;
                }
            }
            __syncthreads();
            // ---- alpha-weighted fp2 partial sums ----
            float s8[8];
#pragma unroll
            for (int i = 0; i < 8; ++i) s8[i] = 0.f;
            {
                const f16* fpb = fp2P + (size_t)b * L_ * G4 + 8 * tid;
#pragma unroll 7
                for (int l = 0; l < L_; ++l) {
                    float a = S->alpha[l];
                    f16x8 fv = *(const f16x8*)&fpb[(size_t)l * G4];
#pragma unroll
                    for (int i = 0; i < 8; ++i) s8[i] += a * (float)fv[i];
                }
            }
            f16x8 ep = *(const f16x8*)&embP[((size_t)b * T_ + t) * G4 + 8 * tid];
            // ---- wait recurrent matmul, read hw (f16, one 16B load) ----
            wait_cnt(&cntW[t * SLOT], NG);
            {
                f16x8 hw = *(const f16x8*)&hwslab[((size_t)t * B_ + b) * G4 + 8 * tid];
                float gA[8];
#pragma unroll
                for (int i = 0; i < 8; ++i) gA[i] = (float)hw[i] + (float)ep[i] + s8[i];
                float cn0 = sigm(gA[1]) * cs0 + sigm(gA[0]) * tanh_f(gA[2]);
                float cn1 = sigm(gA[5]) * cs1 + sigm(gA[4]) * tanh_f(gA[6]);
                float hn0 = sigm(gA[3]) * tanh_f(cn0);
                float hn1 = sigm(gA[7]) * tanh_f(cn1);
                cs0 = cn0; cs1 = cn1;
                union { f16 h[2]; unsigned u; } pk;
                pk.h[0] = (f16)hn0; pk.h[1] = (f16)hn1;
                S->hL[tid] = pk.u;
                ASTORE32((unsigned*)hslab + ((size_t)(t + 1) * B_ + b) * 256 + tid, pk.u);
            }
            __syncthreads();   // drains vmcnt: h sc1 stores acked; hL visible
            if (tid == 0) {
                AADD(&cntH[(t + 1) * SLOT]);      // unblock gemm blocks first
                AADD(&cntH2[(t + 1) * SLOT]);     // mirror for logit blocks
            }
        }
    } else if (bid < 64 + NG) {
        // ======== gemm block g: hidden j in [16g,16g+16) ========
        int g = bid - 64;
        GemmSm* S = (GemmSm*)smraw;
        for (int i = 0; i < 16; ++i) {
            int idx = i * 256 + tid;
            int r = idx >> 6, ch = idx & 63;
            int cc = (r & 3) * 512 + 16 * g + (r >> 2);
            *(f16x8*)&S->w[r][(ch ^ (r & 7)) * 8] =
                *(const f16x8*)&WhhT[(size_t)cc * 512 + ch * 8];
        }
        int wvv = tid >> 6, lane = tid & 63;
        int frow = lane & 15, q = lane >> 4, sw = frow & 7, rq = q * 4;
        int bo = tid >> 2, cq = (tid & 3) * 4;
        __syncthreads();

        for (int t = 0; t < T_; ++t) {
            if (t) wait_cnt(&cntH[t * SLOT], 64);
            {
                const f16* hsrc = hslab + (size_t)t * B_ * H_;
#pragma unroll
                for (int i = 0; i < 16; ++i) {
                    int idx = i * 256 + tid;
                    int r = idx >> 6, ch = idx & 63;
                    *(f16x8*)&S->u.hs[r][(ch ^ (r & 7)) * 8] =
                        *(const f16x8*)&hsrc[(size_t)r * H_ + ch * 8];
                }
            }
            __syncthreads();
            f32x4 a4[4];
#pragma unroll
            for (int mi = 0; mi < 4; ++mi) { a4[mi][0]=0.f; a4[mi][1]=0.f; a4[mi][2]=0.f; a4[mi][3]=0.f; }
#pragma unroll
            for (int kk = 0; kk < 16; ++kk) {
                int ch = ((kk * 4 + q) ^ sw) * 8;
                f16x8 bv = *(f16x8*)&S->w[wvv * 16 + frow][ch];
#pragma unroll
                for (int mi = 0; mi < 4; ++mi) {
                    f16x8 av = *(f16x8*)&S->u.hs[mi * 16 + frow][ch];
                    a4[mi] = __builtin_amdgcn_mfma_f32_16x16x32_f16(av, bv, a4[mi], 0, 0, 0);
                }
            }
            __syncthreads();   // hs reads done before hwT16 overwrite
#pragma unroll
            for (int mi = 0; mi < 4; ++mi)
#pragma unroll
                for (int r = 0; r < 4; ++r)
                    S->u.hwT16[mi * 16 + rq + r][wvv * 16 + frow] = (f16)a4[mi][r];
            __syncthreads();
            // f16 handoff: per instruction, 4 lanes cover 32B contiguous per batch
            {
                f16* dst = hwslab + ((size_t)t * B_ + bo) * G4 + 64 * g + cq;
#pragma unroll
                for (int e = 0; e < 4; ++e) {
                    union { f16 h[4]; ull u; } pk;
                    *(f16x4*)pk.h = *(f16x4*)&S->u.hwT16[bo][cq + 16 * e];
                    ASTORE64(dst + 16 * e, pk.u);
                }
            }
            __syncthreads();   // drains vmcnt: hw stores acked
            if (tid == 0) AADD(&cntW[t * SLOT]);
        }
    } else {
        // ======== logit block: W_out cols [nt*256, nt*256+256) ========
        int nt = bid - 64 - NG;
        int n0 = nt * 256;
        LogSm* S = (LogSm*)smraw;
        int wvv = tid >> 6, lane = tid & 63;
        int frow = lane & 15, q = lane >> 4, sw = frow & 7, rq = q * 4;

        for (int t = 0; t < T_; ++t) {
            wait_cnt(&cntH2[(t + 1) * SLOT], 64);
            {
                const f16* hsrc = hslab + (size_t)(t + 1) * B_ * H_;
#pragma unroll
                for (int i = 0; i < 16; ++i) {
                    int idx = i * 256 + tid;
                    int r = idx >> 6, ch = idx & 63;
                    *(f16x8*)&S->hs[r][(ch ^ (r & 7)) * 8] =
                        *(const f16x8*)&hsrc[(size_t)r * H_ + ch * 8];
                }
            }
            __syncthreads();
            f32x4 acc[4][4];
#pragma unroll
            for (int mi = 0; mi < 4; ++mi)
#pragma unroll
                for (int ni = 0; ni < 4; ++ni) { acc[mi][ni][0]=0.f; acc[mi][ni][1]=0.f; acc[mi][ni][2]=0.f; acc[mi][ni][3]=0.f; }
#pragma unroll 4
            for (int kk = 0; kk < 16; ++kk) {
                int ch = ((kk * 4 + q) ^ sw) * 8;
                f16x8 av[4], bv[4];
#pragma unroll
                for (int mi = 0; mi < 4; ++mi)
                    av[mi] = *(f16x8*)&S->hs[mi * 16 + frow][ch];
#pragma unroll
                for (int ni = 0; ni < 4; ++ni)
                    bv[ni] = *(const f16x8*)&WoutT[(size_t)(n0 + wvv * 64 + ni * 16 + frow) * 512 + kk * 32 + q * 8];
#pragma unroll
                for (int mi = 0; mi < 4; ++mi)
#pragma unroll
                    for (int ni = 0; ni < 4; ++ni)
                        acc[mi][ni] = __builtin_amdgcn_mfma_f32_16x16x32_f16(av[mi], bv[ni], acc[mi][ni], 0, 0, 0);
            }
#pragma unroll
            for (int ni = 0; ni < 4; ++ni) {
                int cc = n0 + wvv * 64 + ni * 16 + frow;
                float badd = b_out[cc];
#pragma unroll
                for (int mi = 0; mi < 4; ++mi)
#pragma unroll
                    for (int r = 0; r < 4; ++r) {
                        int b = mi * 16 + rq + r;
                        preds[((size_t)b * T_ + t) * V_ + cc] = acc[mi][ni][r] + badd;
                    }
            }
        }
    }
}

// ================================================================ launch
extern "C" void kernel_launch(void* const* d_in, const int* in_sizes, int n_in,
                              void* d_out, int out_size, void* d_ws, size_t ws_size,
                              hipStream_t stream) {
    const float* image_feats = (const float*)d_in[0];
    const int*   caption     = (const int*)d_in[1];
    const float* embedding   = (const float*)d_in[2];
    const float* W_init_h    = (const float*)d_in[3];
    const float* b_init_h    = (const float*)d_in[4];
    const float* W_init_c    = (const float*)d_in[5];
    const float* b_init_c    = (const float*)d_in[6];
    const float* W_feat      = (const float*)d_in[7];
    const float* b_feat      = (const float*)d_in[8];
    const float* W_hid       = (const float*)d_in[9];
    const float* b_hid       = (const float*)d_in[10];
    const float* W_score     = (const float*)d_in[11];
    const float* b_score     = (const float*)d_in[12];
    const float* W_ih        = (const float*)d_in[13];
    const float* b_ih        = (const float*)d_in[14];
    const float* W_hh        = (const float*)d_in[15];
    const float* b_hh        = (const float*)d_in[16];
    const float* W_out       = (const float*)d_in[17];
    const float* b_out       = (const float*)d_in[18];

    float* preds = (float*)d_out;                                   // (B,T,V)
    float* out_alpha = preds + (size_t)B_ * T_ * V_;                // (B,T,L)

    size_t off = 0;
    char* base = (char*)d_ws;
    auto carve = [&](size_t bytes) {
        void* p = base + off;
        off += (bytes + 255) & ~(size_t)255;
        return p;
    };
    const int MP = 3200;
    f16* fp2P       = (f16*)carve((size_t)MP * G4 * 2);             // 13.1 MB
    f16* embP       = (f16*)carve((size_t)B_ * T_ * G4 * 2);        // 8.4 MB
    float* featproj = (float*)carve((size_t)B_ * L_ * A_ * 4);      // 3.2 MB
    float* c_cur    = (float*)carve((size_t)B_ * H_ * 4);
    f16* hslab      = (f16*)carve((size_t)(T_ + 1) * B_ * H_ * 2);  // 2.1 MB
    f16* hwslab     = (f16*)carve((size_t)T_ * B_ * G4 * 2);        // 8 MB
    unsigned* cnts  = (unsigned*)carve(3 * (T_ + 2) * SLOT * 4);
    f16* feats16    = (f16*)carve((size_t)MP * F_ * 2);
    f16* embs16     = (f16*)carve((size_t)B_ * T_ * E_ * 2);
    f16* WihT       = (f16*)carve((size_t)G4 * (E_ + F_) * 2);
    f16* WhhT       = (f16*)carve((size_t)G4 * H_ * 2);
    f16* WoutT      = (f16*)carve((size_t)V_ * H_ * 2);
    f16* WhidT      = (f16*)carve((size_t)A_ * H_ * 2);
    unsigned* cntH  = cnts;
    unsigned* cntW  = cnts + (T_ + 2) * SLOT;
    unsigned* cntH2 = cnts + 2 * (T_ + 2) * SLOT;
    (void)ws_size; (void)in_sizes; (void)n_in; (void)out_size;

    // 1) fused prologue
    {
        int nb = NB_TC0 + NB_TC1 + NB_TC2 + NB_TC3 + NB_CVT + NB_EMB + NB_INIT + NB_FP;
        hipLaunchKernelGGL(k_prep, dim3(nb), dim3(256), 0, stream,
                           image_feats, caption, embedding,
                           W_init_h, b_init_h, W_init_c, b_init_c,
                           W_feat, b_feat, W_hid, W_ih, W_hh, W_out,
                           feats16, embs16, WihT, WhhT, WoutT, WhidT,
                           hslab, c_cur, featproj);
    }
    // 2) merged prologue GEMMs: fp2P (400 blocks) + embP (256 blocks)
    hipLaunchKernelGGL(k_gemm_pre, dim3(400 + 256), dim3(256), 0, stream,
                       400,
                       feats16, F_, WihT + E_, E_ + F_, fp2P, B_ * L_, F_, 25,
                       embs16, E_, WihT, E_ + F_, embP, B_ * T_, E_, B_ * T_ / 128,
                       b_ih, b_hh);
    // 3) reset counters
    hipMemsetAsync(cnts, 0, 3 * (T_ + 2) * SLOT * 4, stream);
    // 4) persistent recurrence + shadowed logits (221 blocks, all co-resident)
    hipLaunchKernelGGL(k_steps, dim3(64 + NG + NLOG), dim3(256), 0, stream,
                       WhhT, WhidT, featproj, b_hid, W_score, b_score,
                       embP, fp2P, c_cur, hslab, hwslab,
                       WoutT, b_out, preds, out_alpha,
                       cntH, cntW, cntH2);
}